// Round 16
// baseline (108.108 us; speedup 1.0000x reference)
//
#include <hip/hip_runtime.h>
#include <math.h>

#define SENT 0x007FFFFFu         // fmap(-inf)
#define NEGINF_BITS 0xFF800000u  // raw float -inf
#define NA 256                   // hist/place chunk blocks
#define SB_SHIFT 5               // 32 nodes per bucket
#define SB_MASK ((1u << SB_SHIFT) - 1u)
#define NB 32                    // nodes per bucket
#define PITCH 68                 // LDS row pitch (words)
#define MAXSB 4096
#define CG 768                   // cast sub-grid blocks in merged cast+hist kernel
#define PADROW 32u               // pad edges target LDS scratch row 32
#define RGRID 1024               // persistent fused grid (4 blocks/CU at 512 thr)

typedef __attribute__((ext_vector_type(8))) short bf16x8;
typedef __attribute__((ext_vector_type(4))) float f32x4;

__device__ __forceinline__ unsigned int fmap(float f) {
    unsigned int u = __float_as_uint(f);
    return (u & 0x80000000u) ? ~u : (u | 0x80000000u);
}
__device__ __forceinline__ unsigned int fmap_bits(unsigned int u) {
    return (u & 0x80000000u) ? ~u : (u | 0x80000000u);
}
__device__ __forceinline__ float funmap(unsigned int u) {
    unsigned int bits = (u & 0x80000000u) ? (u ^ 0x80000000u) : ~u;
    return __uint_as_float(bits);
}
__device__ __forceinline__ unsigned short tobf(float f) {
    unsigned int u = __float_as_uint(f);
    u += 0x7FFFu + ((u >> 16) & 1u);
    return (unsigned short)(u >> 16);
}
__device__ __forceinline__ float frombf(unsigned short s) {
    return __uint_as_float((unsigned int)s << 16);
}

// ---------- merged cast (f32->bf16) + per-(sb,blk) histogram + ctrl zero ----------
__global__ void __launch_bounds__(512) casthist_kernel(const float* __restrict__ x,
                                                       unsigned short* __restrict__ xb,
                                                       long long n,
                                                       const int* __restrict__ ei,
                                                       unsigned* __restrict__ counts2,
                                                       unsigned* __restrict__ ctrl,
                                                       int E, int nsb, int chunk) {
    __shared__ unsigned h[MAXSB];
    if ((int)blockIdx.x < CG) {
        long long i = ((long long)blockIdx.x * 512 + threadIdx.x) * 8;
        long long stride = (long long)CG * 512 * 8;
        for (; i < n; i += stride) {
            float4 a = *(const float4*)(x + i);
            float4 c = *(const float4*)(x + i + 4);
            uint4 o;
            o.x = (unsigned)tobf(a.x) | ((unsigned)tobf(a.y) << 16);
            o.y = (unsigned)tobf(a.z) | ((unsigned)tobf(a.w) << 16);
            o.z = (unsigned)tobf(c.x) | ((unsigned)tobf(c.y) << 16);
            o.w = (unsigned)tobf(c.z) | ((unsigned)tobf(c.w) << 16);
            *(uint4*)(xb + i) = o;
        }
    } else {
        int hb = (int)blockIdx.x - CG;
        if (hb == 0 && threadIdx.x == 0) *ctrl = 0u;   // reset last-block counter (every call)
        for (int t = threadIdx.x; t < nsb; t += 512) h[t] = 0u;
        __syncthreads();
        int beg = hb * chunk;
        int end = min(beg + chunk, E);
        for (int i = beg + threadIdx.x; i < end; i += 512)
            atomicAdd(&h[((unsigned)ei[E + i]) >> SB_SHIFT], 1u);
        __syncthreads();
        for (int t = threadIdx.x; t < nsb; t += 512)
            counts2[(size_t)t * NA + hb] = h[t];
    }
}

// standalone hist (Tier B, no cast) + ctrl zero
__global__ void __launch_bounds__(512) histA_kernel(const int* __restrict__ ei,
                                                    unsigned* __restrict__ counts2,
                                                    unsigned* __restrict__ ctrl,
                                                    int E, int nsb, int chunk) {
    __shared__ unsigned h[MAXSB];
    if (blockIdx.x == 0 && threadIdx.x == 0) *ctrl = 0u;
    for (int t = threadIdx.x; t < nsb; t += 512) h[t] = 0u;
    __syncthreads();
    int beg = blockIdx.x * chunk;
    int end = min(beg + chunk, E);
    for (int i = beg + threadIdx.x; i < end; i += 512)
        atomicAdd(&h[((unsigned)ei[E + i]) >> SB_SHIFT], 1u);
    __syncthreads();
    for (int t = threadIdx.x; t < nsb; t += 512)
        counts2[(size_t)t * NA + blockIdx.x] = h[t];
}

// rowscan + fused last-block sbscan (PADDED round-to-16).
__global__ void __launch_bounds__(512) rowscan_kernel(unsigned* __restrict__ counts2,
                                                      unsigned* __restrict__ sbtot,
                                                      unsigned* __restrict__ sbbase,
                                                      unsigned* __restrict__ ctrl, int nsb) {
    __shared__ unsigned wsum[8];
    __shared__ int lastFlag;
    int tid = threadIdx.x;
    int lane = tid & 63;
    int wid = tid >> 6;
    int sb = blockIdx.x * 8 + wid;
    if (sb < nsb) {
        unsigned* row = counts2 + (size_t)sb * NA;
        uint4 v = *(const uint4*)(row + 4 * lane);
        unsigned local = v.x + v.y + v.z + v.w;
        unsigned incl = local;
        #pragma unroll
        for (int d = 1; d < 64; d <<= 1) {
            unsigned t = __shfl_up(incl, d);
            if (lane >= d) incl += t;
        }
        unsigned e0 = incl - local;
        uint4 o;
        o.x = e0;
        o.y = e0 + v.x;
        o.z = o.y + v.y;
        o.w = o.z + v.z;
        *(uint4*)(row + 4 * lane) = o;
        if (lane == 63)
            __hip_atomic_store(&sbtot[sb], incl, __ATOMIC_RELAXED, __HIP_MEMORY_SCOPE_AGENT);
    }
    __syncthreads();
    if (tid == 0) {
        unsigned old = __hip_atomic_fetch_add(ctrl, 1u, __ATOMIC_ACQ_REL, __HIP_MEMORY_SCOPE_AGENT);
        lastFlag = (old == gridDim.x - 1);
    }
    __syncthreads();
    if (!lastFlag) return;

    // ---- final scan over padded sbtot: thread owns 8 consecutive entries ----
    unsigned excl[8];
    unsigned run = 0;
    #pragma unroll
    for (int i = 0; i < 8; ++i) {
        int idx = tid * 8 + i;
        unsigned c = (idx < nsb)
            ? __hip_atomic_load(&sbtot[idx], __ATOMIC_RELAXED, __HIP_MEMORY_SCOPE_AGENT) : 0u;
        c = (c + 15u) & ~15u;
        excl[i] = run;
        run += c;
    }
    unsigned T = run;
    unsigned incl = T;
    #pragma unroll
    for (int d = 1; d < 64; d <<= 1) {
        unsigned t = __shfl_up(incl, d);
        if (lane >= d) incl += t;
    }
    if (lane == 63) wsum[wid] = incl;
    unsigned texcl = incl - T;
    __syncthreads();
    if (wid == 0) {
        unsigned wv = (lane < 8) ? wsum[lane] : 0u;
        unsigned wincl = wv;
        #pragma unroll
        for (int d = 1; d < 8; d <<= 1) {
            unsigned t = __shfl_up(wincl, d);
            if (lane >= d) wincl += t;
        }
        if (lane < 8) wsum[lane] = wincl - wv;
    }
    __syncthreads();
    unsigned base = wsum[wid] + texcl;
    #pragma unroll
    for (int i = 0; i < 8; ++i) {
        int idx = tid * 8 + i;
        if (idx <= nsb) sbbase[idx] = base + excl[i];
    }
}

// placement (blocks [0,NA)) + pad fill (blocks [NA, NA+padB)).
// pack: (src << 6) | (dst & 31); bit5 = 0 for real edges.
__global__ void __launch_bounds__(512) placeB_kernel(const int* __restrict__ ei,
                                                     const unsigned* __restrict__ counts2,
                                                     const unsigned* __restrict__ sbbase,
                                                     const unsigned* __restrict__ sbtot,
                                                     unsigned* __restrict__ ssrc,
                                                     int E, int nsb, int chunk) {
    if ((int)blockIdx.x >= NA) {
        int i = ((int)blockIdx.x - NA) * 512 + threadIdx.x;
        if (i < nsb) {
            unsigned s = sbbase[i] + sbtot[i];
            unsigned e = sbbase[i + 1];
            for (unsigned j = s; j < e; ++j) ssrc[j] = PADROW;
        }
        return;
    }
    __shared__ unsigned fill[MAXSB];
    for (int t = threadIdx.x; t < nsb; t += 512)
        fill[t] = sbbase[t] + counts2[(size_t)t * NA + blockIdx.x];
    __syncthreads();
    int beg = blockIdx.x * chunk;
    int end = min(beg + chunk, E);
    for (int i = beg + threadIdx.x; i < end; i += 512) {
        unsigned src = (unsigned)ei[i];
        unsigned dst = (unsigned)ei[E + i];
        unsigned pos = atomicAdd(&fill[dst >> SB_SHIFT], 1u);
        __builtin_nontemporal_store((src << 6) | (dst & SB_MASK), &ssrc[pos]);
    }
}

// ---------- FUSED segment-max reduce + concat-GEMM-ReLU (512 thr, 8 waves) ----------
// W staged once per persistent block into LDS in MFMA-fragment layout.
__global__ void __launch_bounds__(512) fusedRM_kernel(const unsigned short* __restrict__ xb,
                                                      const unsigned* __restrict__ sbbase,
                                                      const unsigned* __restrict__ ssrc,
                                                      const float* __restrict__ W,
                                                      const float* __restrict__ b,
                                                      float* __restrict__ out,
                                                      int N, int nsb) {
    __shared__ unsigned M[(NB + 1) * PITCH];            // 9.0 KiB (row 32 = pad scratch)
    __shared__ unsigned short Wf[4][4][64][8];          // 16 KiB, frag layout
    int tid = threadIdx.x;
    int lane = tid & 63;
    int wid = tid >> 6;                                 // 8 waves
    int r = lane & 15;
    int g = lane >> 4;

    // ---- stage W fragments (once per block) ----
    // frag(kt,nt): lane l holds B[kt*32+(l>>4)*8+j][nt*16+(l&15)], j=0..7
    for (int idx = tid; idx < 1024; idx += 512) {
        int kt = idx >> 8;
        int nt = (idx >> 6) & 3;
        int l  = idx & 63;
        int k0 = kt * 32 + ((l >> 4) << 3);
        int nn = nt * 16 + (l & 15);
        unsigned short* dst = &Wf[kt][nt][l][0];
        #pragma unroll
        for (int j = 0; j < 8; ++j) dst[j] = tobf(W[(size_t)(k0 + j) * 64 + nn]);
    }
    float bias[4];
    #pragma unroll
    for (int nt = 0; nt < 4; ++nt) bias[nt] = b[nt * 16 + r];

    for (int sb = blockIdx.x; sb < nsb; sb += gridDim.x) {
        for (int i = tid; i < (NB + 1) * PITCH; i += 512) M[i] = SENT;
        int nodeBase = sb * NB;
        int beg = (int)sbbase[sb];
        int end = (int)sbbase[sb + 1];         // padded: multiple of 16
        __syncthreads();                       // covers Wf staging (first iter) + M init

        // ---- gather/reduce phase: 8 waves x 16 edges per iter ----
        for (int i0 = beg + wid * 16; i0 < end; i0 += 128) {
            int si = __builtin_amdgcn_readfirstlane(i0);
            uint4 q0 = *(const uint4*)(ssrc + si);
            uint4 q1 = *(const uint4*)(ssrc + si + 4);
            uint4 q2 = *(const uint4*)(ssrc + si + 8);
            uint4 q3 = *(const uint4*)(ssrc + si + 12);
            unsigned pp[16] = {q0.x, q0.y, q0.z, q0.w, q1.x, q1.y, q1.z, q1.w,
                               q2.x, q2.y, q2.z, q2.w, q3.x, q3.y, q3.z, q3.w};
            unsigned short vv[16];
            #pragma unroll
            for (int k = 0; k < 16; ++k)
                vv[k] = xb[(pp[k] & 0xFFFFFFC0u) | (unsigned)lane];
            #pragma unroll
            for (int k = 0; k < 16; ++k) {
                unsigned u32 = ((unsigned)vv[k]) << 16;
                atomicMax(&M[(pp[k] & 63u) * PITCH + lane], fmap_bits(u32));
            }
        }
        __syncthreads();

        // ---- MFMA epilogue: waves 0,1 each handle one 16-row tile ----
        if (wid < 2) {
            int tb = nodeBase + wid * 16;
            int rowIdx = min(tb + r, N - 1);
            const unsigned short* xp = xb + (size_t)rowIdx * 64;
            int lrow = wid * 16 + r;

            bf16x8 Af[4];
            #pragma unroll
            for (int kt = 0; kt < 2; ++kt)
                Af[kt] = *(const bf16x8*)(xp + kt * 32 + g * 8);
            #pragma unroll
            for (int kt = 0; kt < 2; ++kt) {
                int ch0 = kt * 32 + g * 8;
                uint4 ulo = *(const uint4*)&M[lrow * PITCH + ch0];
                uint4 uhi = *(const uint4*)&M[lrow * PITCH + ch0 + 4];
                unsigned uu[8] = {ulo.x, ulo.y, ulo.z, ulo.w, uhi.x, uhi.y, uhi.z, uhi.w};
                bf16x8 f;
                #pragma unroll
                for (int j = 0; j < 8; ++j) {
                    bool empty = (uu[j] == SENT);
                    float xv = frombf((unsigned short)Af[kt][j]);
                    f[j] = (short)tobf(empty ? 0.0f : (funmap(uu[j]) - xv));
                }
                Af[2 + kt] = f;
            }

            f32x4 acc[4];
            #pragma unroll
            for (int nt = 0; nt < 4; ++nt) {
                f32x4 a = {bias[nt], bias[nt], bias[nt], bias[nt]};
                acc[nt] = a;
            }
            #pragma unroll
            for (int nt = 0; nt < 4; ++nt)
                #pragma unroll
                for (int kt = 0; kt < 4; ++kt) {
                    bf16x8 bf = *(const bf16x8*)&Wf[kt][nt][lane][0];
                    acc[nt] = __builtin_amdgcn_mfma_f32_16x16x32_bf16(Af[kt], bf, acc[nt], 0, 0, 0);
                }

            #pragma unroll
            for (int nt = 0; nt < 4; ++nt)
                #pragma unroll
                for (int reg = 0; reg < 4; ++reg) {
                    int nrow = tb + g * 4 + reg;
                    if (nrow < N)
                        out[(size_t)nrow * 64 + nt * 16 + r] = fmaxf(acc[nt][reg], 0.0f);
                }
        }
        __syncthreads();   // all M reads done before next bucket's re-init
    }
}

// ---------- Tier B (f32 pipeline, same sort machinery) ----------

__global__ void __launch_bounds__(256) reduceB_kernel(const float* __restrict__ x,
                                                      const unsigned* __restrict__ sbbase,
                                                      const unsigned* __restrict__ ssrc,
                                                      float* __restrict__ xj, int N) {
    __shared__ unsigned M[(NB + 1) * PITCH];
    int tid = threadIdx.x;
    int lane = tid & 63;
    int wid = tid >> 6;

    for (int i = tid; i < (NB + 1) * PITCH; i += 256) M[i] = SENT;

    int nodeBase = blockIdx.x * NB;
    int beg = (int)sbbase[blockIdx.x];
    int end = (int)sbbase[blockIdx.x + 1];
    __syncthreads();

    for (int i0 = beg + wid * 16; i0 < end; i0 += 64) {
        int si = __builtin_amdgcn_readfirstlane(i0);
        uint4 q0 = *(const uint4*)(ssrc + si);
        uint4 q1 = *(const uint4*)(ssrc + si + 4);
        uint4 q2 = *(const uint4*)(ssrc + si + 8);
        uint4 q3 = *(const uint4*)(ssrc + si + 12);
        unsigned pp[16] = {q0.x, q0.y, q0.z, q0.w, q1.x, q1.y, q1.z, q1.w,
                           q2.x, q2.y, q2.z, q2.w, q3.x, q3.y, q3.z, q3.w};
        float vv[16];
        #pragma unroll
        for (int k = 0; k < 16; ++k)
            vv[k] = x[(pp[k] & 0xFFFFFFC0u) | (unsigned)lane];
        #pragma unroll
        for (int k = 0; k < 16; ++k)
            atomicMax(&M[(pp[k] & 63u) * PITCH + lane], fmap(vv[k]));
    }
    __syncthreads();

    for (int row = wid; row < NB; row += 4) {
        int n = nodeBase + row;
        if (n < N) xj[(size_t)n * 64 + lane] = funmap(M[row * PITCH + lane]);
    }
}

// MAPPED=true: xj fmap-encoded (atomic fallback); false: raw float with -inf sentinel.
template <bool MAPPED>
__global__ void __launch_bounds__(256) mlp_kernel(const float* __restrict__ x,
                                                  const unsigned int* xj,
                                                  const float* __restrict__ W,
                                                  const float* __restrict__ b,
                                                  float* out, int N) {
    int lane = threadIdx.x & 63;
    int wid  = threadIdx.x >> 6;
    int r = lane & 15;
    int g = lane >> 4;

    bf16x8 Bf[4][4];
    #pragma unroll
    for (int nt = 0; nt < 4; ++nt)
        #pragma unroll
        for (int kt = 0; kt < 4; ++kt) {
            const float* wp = W + (size_t)(kt * 32 + g * 8) * 64 + nt * 16 + r;
            bf16x8 f;
            #pragma unroll
            for (int j = 0; j < 8; ++j) f[j] = (short)tobf(wp[(size_t)j * 64]);
            Bf[nt][kt] = f;
        }
    float bias[4];
    #pragma unroll
    for (int nt = 0; nt < 4; ++nt) bias[nt] = b[nt * 16 + r];

    int nTiles = (N + 15) >> 4;
    int totalWaves = gridDim.x * 4;
    for (int tile = blockIdx.x * 4 + wid; tile < nTiles; tile += totalWaves) {
        int nodeBase = tile << 4;
        int rowIdx = min(nodeBase + r, N - 1);
        const float* xp = x + (size_t)rowIdx * 64;
        const unsigned int* jp = xj + (size_t)rowIdx * 64;

        bf16x8 Af[4];
        float xs[2][8];
        #pragma unroll
        for (int kt = 0; kt < 2; ++kt) {
            float4 flo = *(const float4*)(xp + kt * 32 + g * 8);
            float4 fhi = *(const float4*)(xp + kt * 32 + g * 8 + 4);
            xs[kt][0] = flo.x; xs[kt][1] = flo.y; xs[kt][2] = flo.z; xs[kt][3] = flo.w;
            xs[kt][4] = fhi.x; xs[kt][5] = fhi.y; xs[kt][6] = fhi.z; xs[kt][7] = fhi.w;
            bf16x8 f;
            #pragma unroll
            for (int j = 0; j < 8; ++j) f[j] = (short)tobf(xs[kt][j]);
            Af[kt] = f;
        }
        #pragma unroll
        for (int kt = 0; kt < 2; ++kt) {
            uint4 ulo = *(const uint4*)(jp + kt * 32 + g * 8);
            uint4 uhi = *(const uint4*)(jp + kt * 32 + g * 8 + 4);
            unsigned int uu[8] = {ulo.x, ulo.y, ulo.z, ulo.w, uhi.x, uhi.y, uhi.z, uhi.w};
            bf16x8 f;
            #pragma unroll
            for (int j = 0; j < 8; ++j) {
                bool empty;
                float v;
                if (MAPPED) { empty = (uu[j] == SENT); v = funmap(uu[j]); }
                else        { empty = (uu[j] == NEGINF_BITS); v = __uint_as_float(uu[j]); }
                f[j] = (short)tobf(empty ? 0.0f : (v - xs[kt][j]));
            }
            Af[2 + kt] = f;
        }

        f32x4 acc[4];
        #pragma unroll
        for (int nt = 0; nt < 4; ++nt) {
            f32x4 a = {bias[nt], bias[nt], bias[nt], bias[nt]};
            acc[nt] = a;
        }
        #pragma unroll
        for (int nt = 0; nt < 4; ++nt)
            #pragma unroll
            for (int kt = 0; kt < 4; ++kt)
                acc[nt] = __builtin_amdgcn_mfma_f32_16x16x32_bf16(Af[kt], Bf[nt][kt], acc[nt], 0, 0, 0);

        #pragma unroll
        for (int nt = 0; nt < 4; ++nt)
            #pragma unroll
            for (int reg = 0; reg < 4; ++reg) {
                int nrow = nodeBase + g * 4 + reg;
                if (nrow < N)
                    out[(size_t)nrow * 64 + nt * 16 + r] = fmaxf(acc[nt][reg], 0.0f);
            }
    }
}

// ---------------- atomic fallback (Tier C) ----------------

__global__ void init_kernel(uint4* __restrict__ ws, int n4) {
    int i = blockIdx.x * blockDim.x + threadIdx.x;
    int stride = gridDim.x * blockDim.x;
    uint4 v = make_uint4(SENT, SENT, SENT, SENT);
    for (; i < n4; i += stride) ws[i] = v;
}

__global__ void scatter_kernel(const float* __restrict__ x,
                               const int* __restrict__ ei,
                               unsigned int* __restrict__ ws, int E) {
    long long gid = (long long)blockIdx.x * blockDim.x + threadIdx.x;
    int e = (int)(gid >> 6);
    int lane = (int)(gid & 63);
    if (e >= E) return;
    int src = ei[e];
    int dst = ei[E + e];
    unsigned int m = fmap(x[(size_t)src * 64 + lane]);
    unsigned int* p = ws + (size_t)dst * 64 + lane;
    if (m > *p) atomicMax(p, m);
}

extern "C" void kernel_launch(void* const* d_in, const int* in_sizes, int n_in,
                              void* d_out, int out_size, void* d_ws, size_t ws_size,
                              hipStream_t stream) {
    const float* x  = (const float*)d_in[0];
    const int*   ei = (const int*)d_in[1];
    const float* W  = (const float*)d_in[2];
    const float* b  = (const float*)d_in[3];
    float* out = (float*)d_out;

    int N = in_sizes[0] / 64;
    int E = in_sizes[1] / 2;

    int nsb = (N + NB - 1) >> SB_SHIFT;
    int chunk = (E + NA - 1) / NA;
    int padB = (nsb + 511) / 512;

    size_t counts2_b = (size_t)nsb * NA * 4;
    size_t sbtot_b   = (size_t)((nsb + 63) & ~63) * 4;
    size_t sbbase_b  = (size_t)(nsb + 1 + 63) / 64 * 64 * 4;
    size_t ctrl_b    = 64;
    size_t ssrc_b    = ((size_t)E + 16u * (size_t)nsb) * 4;   // padded to 16/bucket
    size_t xb_b      = (size_t)N * 64 * 2;
    size_t xj32_b    = (size_t)N * 64 * 4;
    size_t needB     = counts2_b + sbtot_b + sbbase_b + ctrl_b + ssrc_b;
    size_t needA     = needB + xb_b;

    int mgrid = (((N + 15) >> 4) + 3) / 4;
    int rsgrid = (nsb + 7) / 8;

    if (ws_size >= needA && nsb <= MAXSB) {
        // Tier A: bf16 fused pipeline (4 launches)
        char* p = (char*)d_ws;
        unsigned* counts2 = (unsigned*)p; p += counts2_b;
        unsigned* sbtot   = (unsigned*)p; p += sbtot_b;
        unsigned* sbbase  = (unsigned*)p; p += sbbase_b;
        unsigned* ctrl    = (unsigned*)p; p += ctrl_b;
        unsigned* ssrc    = (unsigned*)p; p += ssrc_b;
        unsigned short* xb = (unsigned short*)p;

        long long n = (long long)N * 64;
        casthist_kernel<<<CG + NA, 512, 0, stream>>>(x, xb, n, ei, counts2, ctrl, E, nsb, chunk);
        rowscan_kernel<<<rsgrid, 512, 0, stream>>>(counts2, sbtot, sbbase, ctrl, nsb);
        placeB_kernel<<<NA + padB, 512, 0, stream>>>(ei, counts2, sbbase, sbtot, ssrc, E, nsb, chunk);
        int rgrid = (nsb < RGRID) ? nsb : RGRID;
        fusedRM_kernel<<<rgrid, 512, 0, stream>>>(xb, sbbase, ssrc, W, b, out, N, nsb);
    } else if (ws_size >= needB && nsb <= MAXSB) {
        // Tier B: f32 pipeline
        char* p = (char*)d_ws;
        unsigned* counts2 = (unsigned*)p; p += counts2_b;
        unsigned* sbtot   = (unsigned*)p; p += sbtot_b;
        unsigned* sbbase  = (unsigned*)p; p += sbbase_b;
        unsigned* ctrl    = (unsigned*)p; p += ctrl_b;
        unsigned* ssrc    = (unsigned*)p; p += ssrc_b;
        float* xjp = (ws_size >= needB + xj32_b) ? (float*)p : (float*)d_out;

        histA_kernel<<<NA, 512, 0, stream>>>(ei, counts2, ctrl, E, nsb, chunk);
        rowscan_kernel<<<rsgrid, 512, 0, stream>>>(counts2, sbtot, sbbase, ctrl, nsb);
        placeB_kernel<<<NA + padB, 512, 0, stream>>>(ei, counts2, sbbase, sbtot, ssrc, E, nsb, chunk);
        reduceB_kernel<<<nsb, 256, 0, stream>>>(x, sbbase, ssrc, xjp, N);
        mlp_kernel<false><<<mgrid, 256, 0, stream>>>(x, (const unsigned*)xjp, W, b, out, N);
    } else {
        // Tier C: atomic fallback
        size_t need2 = (size_t)N * 64 * 4;
        unsigned int* scratch = (ws_size >= need2) ? (unsigned int*)d_ws : (unsigned int*)d_out;
        init_kernel<<<2048, 256, 0, stream>>>((uint4*)scratch, N * 16);
        long long sthreads = (long long)E * 64;
        int sblocks = (int)((sthreads + 255) / 256);
        scatter_kernel<<<sblocks, 256, 0, stream>>>(x, ei, scratch, E);
        mlp_kernel<true><<<mgrid, 256, 0, stream>>>(x, scratch, W, b, out, N);
    }
}

// Round 17
// 86.979 us; speedup vs baseline: 1.2429x; 1.2429x over previous
//
#include <hip/hip_runtime.h>
#include <math.h>

#define SENT 0x007FFFFFu         // fmap(-inf)
#define NEGINF_BITS 0xFF800000u  // raw float -inf
#define NA 256                   // hist/place chunk blocks
#define SB_SHIFT 5               // 32 nodes per bucket
#define SB_MASK ((1u << SB_SHIFT) - 1u)
#define NB 32                    // nodes per bucket
#define PITCH 68                 // LDS row pitch (words)
#define MAXSB 4096
#define CG 768                   // cast sub-grid blocks in merged cast+hist kernel
#define PADROW 32u               // pad edges target LDS scratch row 32
#define RGRID 2048               // persistent fused grid

typedef __attribute__((ext_vector_type(8))) short bf16x8;
typedef __attribute__((ext_vector_type(4))) float f32x4;

__device__ __forceinline__ unsigned int fmap(float f) {
    unsigned int u = __float_as_uint(f);
    return (u & 0x80000000u) ? ~u : (u | 0x80000000u);
}
__device__ __forceinline__ unsigned int fmap_bits(unsigned int u) {
    return (u & 0x80000000u) ? ~u : (u | 0x80000000u);
}
__device__ __forceinline__ float funmap(unsigned int u) {
    unsigned int bits = (u & 0x80000000u) ? (u ^ 0x80000000u) : ~u;
    return __uint_as_float(bits);
}
__device__ __forceinline__ unsigned short tobf(float f) {
    unsigned int u = __float_as_uint(f);
    u += 0x7FFFu + ((u >> 16) & 1u);
    return (unsigned short)(u >> 16);
}
__device__ __forceinline__ float frombf(unsigned short s) {
    return __uint_as_float((unsigned int)s << 16);
}

// ---------- merged cast (f32->bf16) + per-(sb,blk) histogram + ctrl zero ----------
__global__ void __launch_bounds__(512) casthist_kernel(const float* __restrict__ x,
                                                       unsigned short* __restrict__ xb,
                                                       long long n,
                                                       const int* __restrict__ ei,
                                                       unsigned* __restrict__ counts2,
                                                       unsigned* __restrict__ ctrl,
                                                       int E, int nsb, int chunk) {
    __shared__ unsigned h[MAXSB];
    if ((int)blockIdx.x < CG) {
        long long i = ((long long)blockIdx.x * 512 + threadIdx.x) * 8;
        long long stride = (long long)CG * 512 * 8;
        for (; i < n; i += stride) {
            float4 a = *(const float4*)(x + i);
            float4 c = *(const float4*)(x + i + 4);
            uint4 o;
            o.x = (unsigned)tobf(a.x) | ((unsigned)tobf(a.y) << 16);
            o.y = (unsigned)tobf(a.z) | ((unsigned)tobf(a.w) << 16);
            o.z = (unsigned)tobf(c.x) | ((unsigned)tobf(c.y) << 16);
            o.w = (unsigned)tobf(c.z) | ((unsigned)tobf(c.w) << 16);
            *(uint4*)(xb + i) = o;
        }
    } else {
        int hb = (int)blockIdx.x - CG;
        if (hb == 0 && threadIdx.x == 0) *ctrl = 0u;   // reset last-block counter (every call)
        for (int t = threadIdx.x; t < nsb; t += 512) h[t] = 0u;
        __syncthreads();
        int beg = hb * chunk;
        int end = min(beg + chunk, E);
        for (int i = beg + threadIdx.x; i < end; i += 512)
            atomicAdd(&h[((unsigned)ei[E + i]) >> SB_SHIFT], 1u);
        __syncthreads();
        for (int t = threadIdx.x; t < nsb; t += 512)
            counts2[(size_t)t * NA + hb] = h[t];
    }
}

// standalone hist (Tier B, no cast) + ctrl zero
__global__ void __launch_bounds__(512) histA_kernel(const int* __restrict__ ei,
                                                    unsigned* __restrict__ counts2,
                                                    unsigned* __restrict__ ctrl,
                                                    int E, int nsb, int chunk) {
    __shared__ unsigned h[MAXSB];
    if (blockIdx.x == 0 && threadIdx.x == 0) *ctrl = 0u;
    for (int t = threadIdx.x; t < nsb; t += 512) h[t] = 0u;
    __syncthreads();
    int beg = blockIdx.x * chunk;
    int end = min(beg + chunk, E);
    for (int i = beg + threadIdx.x; i < end; i += 512)
        atomicAdd(&h[((unsigned)ei[E + i]) >> SB_SHIFT], 1u);
    __syncthreads();
    for (int t = threadIdx.x; t < nsb; t += 512)
        counts2[(size_t)t * NA + blockIdx.x] = h[t];
}

// rowscan + fused last-block sbscan (PADDED round-to-16).
__global__ void __launch_bounds__(512) rowscan_kernel(unsigned* __restrict__ counts2,
                                                      unsigned* __restrict__ sbtot,
                                                      unsigned* __restrict__ sbbase,
                                                      unsigned* __restrict__ ctrl, int nsb) {
    __shared__ unsigned wsum[8];
    __shared__ int lastFlag;
    int tid = threadIdx.x;
    int lane = tid & 63;
    int wid = tid >> 6;
    int sb = blockIdx.x * 8 + wid;
    if (sb < nsb) {
        unsigned* row = counts2 + (size_t)sb * NA;
        uint4 v = *(const uint4*)(row + 4 * lane);
        unsigned local = v.x + v.y + v.z + v.w;
        unsigned incl = local;
        #pragma unroll
        for (int d = 1; d < 64; d <<= 1) {
            unsigned t = __shfl_up(incl, d);
            if (lane >= d) incl += t;
        }
        unsigned e0 = incl - local;
        uint4 o;
        o.x = e0;
        o.y = e0 + v.x;
        o.z = o.y + v.y;
        o.w = o.z + v.z;
        *(uint4*)(row + 4 * lane) = o;
        if (lane == 63)
            __hip_atomic_store(&sbtot[sb], incl, __ATOMIC_RELAXED, __HIP_MEMORY_SCOPE_AGENT);
    }
    __syncthreads();
    if (tid == 0) {
        unsigned old = __hip_atomic_fetch_add(ctrl, 1u, __ATOMIC_ACQ_REL, __HIP_MEMORY_SCOPE_AGENT);
        lastFlag = (old == gridDim.x - 1);
    }
    __syncthreads();
    if (!lastFlag) return;

    // ---- final scan over padded sbtot: thread owns 8 consecutive entries ----
    unsigned excl[8];
    unsigned run = 0;
    #pragma unroll
    for (int i = 0; i < 8; ++i) {
        int idx = tid * 8 + i;
        unsigned c = (idx < nsb)
            ? __hip_atomic_load(&sbtot[idx], __ATOMIC_RELAXED, __HIP_MEMORY_SCOPE_AGENT) : 0u;
        c = (c + 15u) & ~15u;
        excl[i] = run;
        run += c;
    }
    unsigned T = run;
    unsigned incl = T;
    #pragma unroll
    for (int d = 1; d < 64; d <<= 1) {
        unsigned t = __shfl_up(incl, d);
        if (lane >= d) incl += t;
    }
    if (lane == 63) wsum[wid] = incl;
    unsigned texcl = incl - T;
    __syncthreads();
    if (wid == 0) {
        unsigned wv = (lane < 8) ? wsum[lane] : 0u;
        unsigned wincl = wv;
        #pragma unroll
        for (int d = 1; d < 8; d <<= 1) {
            unsigned t = __shfl_up(wincl, d);
            if (lane >= d) wincl += t;
        }
        if (lane < 8) wsum[lane] = wincl - wv;
    }
    __syncthreads();
    unsigned base = wsum[wid] + texcl;
    #pragma unroll
    for (int i = 0; i < 8; ++i) {
        int idx = tid * 8 + i;
        if (idx <= nsb) sbbase[idx] = base + excl[i];
    }
}

// placement (blocks [0,NA)) + pad fill (blocks [NA, NA+padB)).
// pack: (src << 6) | (dst & 31); bit5 = 0 for real edges.
__global__ void __launch_bounds__(512) placeB_kernel(const int* __restrict__ ei,
                                                     const unsigned* __restrict__ counts2,
                                                     const unsigned* __restrict__ sbbase,
                                                     const unsigned* __restrict__ sbtot,
                                                     unsigned* __restrict__ ssrc,
                                                     int E, int nsb, int chunk) {
    if ((int)blockIdx.x >= NA) {
        int i = ((int)blockIdx.x - NA) * 512 + threadIdx.x;
        if (i < nsb) {
            unsigned s = sbbase[i] + sbtot[i];
            unsigned e = sbbase[i + 1];
            for (unsigned j = s; j < e; ++j) ssrc[j] = PADROW;
        }
        return;
    }
    __shared__ unsigned fill[MAXSB];
    for (int t = threadIdx.x; t < nsb; t += 512)
        fill[t] = sbbase[t] + counts2[(size_t)t * NA + blockIdx.x];
    __syncthreads();
    int beg = blockIdx.x * chunk;
    int end = min(beg + chunk, E);
    for (int i = beg + threadIdx.x; i < end; i += 512) {
        unsigned src = (unsigned)ei[i];
        unsigned dst = (unsigned)ei[E + i];
        unsigned pos = atomicAdd(&fill[dst >> SB_SHIFT], 1u);
        ssrc[pos] = (src << 6) | (dst & SB_MASK);
    }
}

// ---------- FUSED segment-max reduce + concat-GEMM-ReLU (256 thr, 4 waves) ----------
// Persistent grid. W staged ONCE per block into LDS in MFMA-fragment layout
// (Wf[kt][nt][lane][8], bf16) -> epilogue B-frags are single conflict-free
// ds_read_b128, keeping VGPR low (R8's failure was register-resident Bf).
__global__ void __launch_bounds__(256) fusedRM_kernel(const unsigned short* __restrict__ xb,
                                                      const unsigned* __restrict__ sbbase,
                                                      const unsigned* __restrict__ ssrc,
                                                      const float* __restrict__ W,
                                                      const float* __restrict__ b,
                                                      float* __restrict__ out,
                                                      int N, int nsb) {
    __shared__ unsigned M[(NB + 1) * PITCH];            // 9.0 KiB (row 32 = pad scratch)
    __shared__ unsigned short Wf[4][4][64][8];          // 16 KiB, frag layout
    int tid = threadIdx.x;
    int lane = tid & 63;
    int wid = tid >> 6;                                 // 4 waves
    int r = lane & 15;
    int g = lane >> 4;

    // ---- stage W fragments (once per block) ----
    // frag(kt,nt): lane l holds B[kt*32+(l>>4)*8+j][nt*16+(l&15)], j=0..7
    for (int idx = tid; idx < 1024; idx += 256) {
        int kt = idx >> 8;
        int nt = (idx >> 6) & 3;
        int l  = idx & 63;
        int k0 = kt * 32 + ((l >> 4) << 3);
        int nn = nt * 16 + (l & 15);
        unsigned short* dst = &Wf[kt][nt][l][0];
        #pragma unroll
        for (int j = 0; j < 8; ++j) dst[j] = tobf(W[(size_t)(k0 + j) * 64 + nn]);
    }
    float bias[4];
    #pragma unroll
    for (int nt = 0; nt < 4; ++nt) bias[nt] = b[nt * 16 + r];

    for (int sb = blockIdx.x; sb < nsb; sb += gridDim.x) {
        for (int i = tid; i < (NB + 1) * PITCH; i += 256) M[i] = SENT;
        int nodeBase = sb * NB;
        int beg = (int)sbbase[sb];
        int end = (int)sbbase[sb + 1];         // padded: multiple of 16
        __syncthreads();                       // covers Wf staging (first iter) + M init

        // ---- gather/reduce phase ----
        for (int i0 = beg + wid * 16; i0 < end; i0 += 64) {
            int si = __builtin_amdgcn_readfirstlane(i0);
            uint4 q0 = *(const uint4*)(ssrc + si);
            uint4 q1 = *(const uint4*)(ssrc + si + 4);
            uint4 q2 = *(const uint4*)(ssrc + si + 8);
            uint4 q3 = *(const uint4*)(ssrc + si + 12);
            unsigned pp[16] = {q0.x, q0.y, q0.z, q0.w, q1.x, q1.y, q1.z, q1.w,
                               q2.x, q2.y, q2.z, q2.w, q3.x, q3.y, q3.z, q3.w};
            unsigned short vv[16];
            #pragma unroll
            for (int k = 0; k < 16; ++k)
                vv[k] = xb[(pp[k] & 0xFFFFFFC0u) | (unsigned)lane];
            #pragma unroll
            for (int k = 0; k < 16; ++k) {
                unsigned u32 = ((unsigned)vv[k]) << 16;
                atomicMax(&M[(pp[k] & 63u) * PITCH + lane], fmap_bits(u32));
            }
        }
        __syncthreads();

        // ---- MFMA epilogue: waves 0,1 each handle one 16-row tile ----
        if (wid < 2) {
            int tb = nodeBase + wid * 16;
            int rowIdx = min(tb + r, N - 1);
            const unsigned short* xp = xb + (size_t)rowIdx * 64;
            int lrow = wid * 16 + r;

            bf16x8 Af[4];
            #pragma unroll
            for (int kt = 0; kt < 2; ++kt)
                Af[kt] = *(const bf16x8*)(xp + kt * 32 + g * 8);
            #pragma unroll
            for (int kt = 0; kt < 2; ++kt) {
                int ch0 = kt * 32 + g * 8;
                uint4 ulo = *(const uint4*)&M[lrow * PITCH + ch0];
                uint4 uhi = *(const uint4*)&M[lrow * PITCH + ch0 + 4];
                unsigned uu[8] = {ulo.x, ulo.y, ulo.z, ulo.w, uhi.x, uhi.y, uhi.z, uhi.w};
                bf16x8 f;
                #pragma unroll
                for (int j = 0; j < 8; ++j) {
                    bool empty = (uu[j] == SENT);
                    float xv = frombf((unsigned short)Af[kt][j]);
                    f[j] = (short)tobf(empty ? 0.0f : (funmap(uu[j]) - xv));
                }
                Af[2 + kt] = f;
            }

            f32x4 acc[4];
            #pragma unroll
            for (int nt = 0; nt < 4; ++nt) {
                f32x4 a = {bias[nt], bias[nt], bias[nt], bias[nt]};
                acc[nt] = a;
            }
            #pragma unroll
            for (int nt = 0; nt < 4; ++nt)
                #pragma unroll
                for (int kt = 0; kt < 4; ++kt) {
                    bf16x8 bf = *(const bf16x8*)&Wf[kt][nt][lane][0];
                    acc[nt] = __builtin_amdgcn_mfma_f32_16x16x32_bf16(Af[kt], bf, acc[nt], 0, 0, 0);
                }

            #pragma unroll
            for (int nt = 0; nt < 4; ++nt)
                #pragma unroll
                for (int reg = 0; reg < 4; ++reg) {
                    int nrow = tb + g * 4 + reg;
                    if (nrow < N)
                        out[(size_t)nrow * 64 + nt * 16 + r] = fmaxf(acc[nt][reg], 0.0f);
                }
        }
        __syncthreads();   // all M reads done before next bucket's re-init
    }
}

// ---------- Tier B (f32 pipeline, same sort machinery) ----------

__global__ void __launch_bounds__(256) reduceB_kernel(const float* __restrict__ x,
                                                      const unsigned* __restrict__ sbbase,
                                                      const unsigned* __restrict__ ssrc,
                                                      float* __restrict__ xj, int N) {
    __shared__ unsigned M[(NB + 1) * PITCH];
    int tid = threadIdx.x;
    int lane = tid & 63;
    int wid = tid >> 6;

    for (int i = tid; i < (NB + 1) * PITCH; i += 256) M[i] = SENT;

    int nodeBase = blockIdx.x * NB;
    int beg = (int)sbbase[blockIdx.x];
    int end = (int)sbbase[blockIdx.x + 1];
    __syncthreads();

    for (int i0 = beg + wid * 16; i0 < end; i0 += 64) {
        int si = __builtin_amdgcn_readfirstlane(i0);
        uint4 q0 = *(const uint4*)(ssrc + si);
        uint4 q1 = *(const uint4*)(ssrc + si + 4);
        uint4 q2 = *(const uint4*)(ssrc + si + 8);
        uint4 q3 = *(const uint4*)(ssrc + si + 12);
        unsigned pp[16] = {q0.x, q0.y, q0.z, q0.w, q1.x, q1.y, q1.z, q1.w,
                           q2.x, q2.y, q2.z, q2.w, q3.x, q3.y, q3.z, q3.w};
        float vv[16];
        #pragma unroll
        for (int k = 0; k < 16; ++k)
            vv[k] = x[(pp[k] & 0xFFFFFFC0u) | (unsigned)lane];
        #pragma unroll
        for (int k = 0; k < 16; ++k)
            atomicMax(&M[(pp[k] & 63u) * PITCH + lane], fmap(vv[k]));
    }
    __syncthreads();

    for (int row = wid; row < NB; row += 4) {
        int n = nodeBase + row;
        if (n < N) xj[(size_t)n * 64 + lane] = funmap(M[row * PITCH + lane]);
    }
}

// MAPPED=true: xj fmap-encoded (atomic fallback); false: raw float with -inf sentinel.
template <bool MAPPED>
__global__ void __launch_bounds__(256) mlp_kernel(const float* __restrict__ x,
                                                  const unsigned int* xj,
                                                  const float* __restrict__ W,
                                                  const float* __restrict__ b,
                                                  float* out, int N) {
    int lane = threadIdx.x & 63;
    int wid  = threadIdx.x >> 6;
    int r = lane & 15;
    int g = lane >> 4;

    bf16x8 Bf[4][4];
    #pragma unroll
    for (int nt = 0; nt < 4; ++nt)
        #pragma unroll
        for (int kt = 0; kt < 4; ++kt) {
            const float* wp = W + (size_t)(kt * 32 + g * 8) * 64 + nt * 16 + r;
            bf16x8 f;
            #pragma unroll
            for (int j = 0; j < 8; ++j) f[j] = (short)tobf(wp[(size_t)j * 64]);
            Bf[nt][kt] = f;
        }
    float bias[4];
    #pragma unroll
    for (int nt = 0; nt < 4; ++nt) bias[nt] = b[nt * 16 + r];

    int nTiles = (N + 15) >> 4;
    int totalWaves = gridDim.x * 4;
    for (int tile = blockIdx.x * 4 + wid; tile < nTiles; tile += totalWaves) {
        int nodeBase = tile << 4;
        int rowIdx = min(nodeBase + r, N - 1);
        const float* xp = x + (size_t)rowIdx * 64;
        const unsigned int* jp = xj + (size_t)rowIdx * 64;

        bf16x8 Af[4];
        float xs[2][8];
        #pragma unroll
        for (int kt = 0; kt < 2; ++kt) {
            float4 flo = *(const float4*)(xp + kt * 32 + g * 8);
            float4 fhi = *(const float4*)(xp + kt * 32 + g * 8 + 4);
            xs[kt][0] = flo.x; xs[kt][1] = flo.y; xs[kt][2] = flo.z; xs[kt][3] = flo.w;
            xs[kt][4] = fhi.x; xs[kt][5] = fhi.y; xs[kt][6] = fhi.z; xs[kt][7] = fhi.w;
            bf16x8 f;
            #pragma unroll
            for (int j = 0; j < 8; ++j) f[j] = (short)tobf(xs[kt][j]);
            Af[kt] = f;
        }
        #pragma unroll
        for (int kt = 0; kt < 2; ++kt) {
            uint4 ulo = *(const uint4*)(jp + kt * 32 + g * 8);
            uint4 uhi = *(const uint4*)(jp + kt * 32 + g * 8 + 4);
            unsigned int uu[8] = {ulo.x, ulo.y, ulo.z, ulo.w, uhi.x, uhi.y, uhi.z, uhi.w};
            bf16x8 f;
            #pragma unroll
            for (int j = 0; j < 8; ++j) {
                bool empty;
                float v;
                if (MAPPED) { empty = (uu[j] == SENT); v = funmap(uu[j]); }
                else        { empty = (uu[j] == NEGINF_BITS); v = __uint_as_float(uu[j]); }
                f[j] = (short)tobf(empty ? 0.0f : (v - xs[kt][j]));
            }
            Af[2 + kt] = f;
        }

        f32x4 acc[4];
        #pragma unroll
        for (int nt = 0; nt < 4; ++nt) {
            f32x4 a = {bias[nt], bias[nt], bias[nt], bias[nt]};
            acc[nt] = a;
        }
        #pragma unroll
        for (int nt = 0; nt < 4; ++nt)
            #pragma unroll
            for (int kt = 0; kt < 4; ++kt)
                acc[nt] = __builtin_amdgcn_mfma_f32_16x16x32_bf16(Af[kt], Bf[nt][kt], acc[nt], 0, 0, 0);

        #pragma unroll
        for (int nt = 0; nt < 4; ++nt)
            #pragma unroll
            for (int reg = 0; reg < 4; ++reg) {
                int nrow = nodeBase + g * 4 + reg;
                if (nrow < N)
                    out[(size_t)nrow * 64 + nt * 16 + r] = fmaxf(acc[nt][reg], 0.0f);
            }
    }
}

// ---------------- atomic fallback (Tier C) ----------------

__global__ void init_kernel(uint4* __restrict__ ws, int n4) {
    int i = blockIdx.x * blockDim.x + threadIdx.x;
    int stride = gridDim.x * blockDim.x;
    uint4 v = make_uint4(SENT, SENT, SENT, SENT);
    for (; i < n4; i += stride) ws[i] = v;
}

__global__ void scatter_kernel(const float* __restrict__ x,
                               const int* __restrict__ ei,
                               unsigned int* __restrict__ ws, int E) {
    long long gid = (long long)blockIdx.x * blockDim.x + threadIdx.x;
    int e = (int)(gid >> 6);
    int lane = (int)(gid & 63);
    if (e >= E) return;
    int src = ei[e];
    int dst = ei[E + e];
    unsigned int m = fmap(x[(size_t)src * 64 + lane]);
    unsigned int* p = ws + (size_t)dst * 64 + lane;
    if (m > *p) atomicMax(p, m);
}

extern "C" void kernel_launch(void* const* d_in, const int* in_sizes, int n_in,
                              void* d_out, int out_size, void* d_ws, size_t ws_size,
                              hipStream_t stream) {
    const float* x  = (const float*)d_in[0];
    const int*   ei = (const int*)d_in[1];
    const float* W  = (const float*)d_in[2];
    const float* b  = (const float*)d_in[3];
    float* out = (float*)d_out;

    int N = in_sizes[0] / 64;
    int E = in_sizes[1] / 2;

    int nsb = (N + NB - 1) >> SB_SHIFT;
    int chunk = (E + NA - 1) / NA;
    int padB = (nsb + 511) / 512;

    size_t counts2_b = (size_t)nsb * NA * 4;
    size_t sbtot_b   = (size_t)((nsb + 63) & ~63) * 4;
    size_t sbbase_b  = (size_t)(nsb + 1 + 63) / 64 * 64 * 4;
    size_t ctrl_b    = 64;
    size_t ssrc_b    = ((size_t)E + 16u * (size_t)nsb) * 4;   // padded to 16/bucket
    size_t xb_b      = (size_t)N * 64 * 2;
    size_t xj32_b    = (size_t)N * 64 * 4;
    size_t needB     = counts2_b + sbtot_b + sbbase_b + ctrl_b + ssrc_b;
    size_t needA     = needB + xb_b;

    int mgrid = (((N + 15) >> 4) + 3) / 4;
    int rsgrid = (nsb + 7) / 8;

    if (ws_size >= needA && nsb <= MAXSB) {
        // Tier A: bf16 fused pipeline (4 launches)
        char* p = (char*)d_ws;
        unsigned* counts2 = (unsigned*)p; p += counts2_b;
        unsigned* sbtot   = (unsigned*)p; p += sbtot_b;
        unsigned* sbbase  = (unsigned*)p; p += sbbase_b;
        unsigned* ctrl    = (unsigned*)p; p += ctrl_b;
        unsigned* ssrc    = (unsigned*)p; p += ssrc_b;
        unsigned short* xb = (unsigned short*)p;

        long long n = (long long)N * 64;
        casthist_kernel<<<CG + NA, 512, 0, stream>>>(x, xb, n, ei, counts2, ctrl, E, nsb, chunk);
        rowscan_kernel<<<rsgrid, 512, 0, stream>>>(counts2, sbtot, sbbase, ctrl, nsb);
        placeB_kernel<<<NA + padB, 512, 0, stream>>>(ei, counts2, sbbase, sbtot, ssrc, E, nsb, chunk);
        int rgrid = (nsb < RGRID) ? nsb : RGRID;
        fusedRM_kernel<<<rgrid, 256, 0, stream>>>(xb, sbbase, ssrc, W, b, out, N, nsb);
    } else if (ws_size >= needB && nsb <= MAXSB) {
        // Tier B: f32 pipeline
        char* p = (char*)d_ws;
        unsigned* counts2 = (unsigned*)p; p += counts2_b;
        unsigned* sbtot   = (unsigned*)p; p += sbtot_b;
        unsigned* sbbase  = (unsigned*)p; p += sbbase_b;
        unsigned* ctrl    = (unsigned*)p; p += ctrl_b;
        unsigned* ssrc    = (unsigned*)p; p += ssrc_b;
        float* xjp = (ws_size >= needB + xj32_b) ? (float*)p : (float*)d_out;

        histA_kernel<<<NA, 512, 0, stream>>>(ei, counts2, ctrl, E, nsb, chunk);
        rowscan_kernel<<<rsgrid, 512, 0, stream>>>(counts2, sbtot, sbbase, ctrl, nsb);
        placeB_kernel<<<NA + padB, 512, 0, stream>>>(ei, counts2, sbbase, sbtot, ssrc, E, nsb, chunk);
        reduceB_kernel<<<nsb, 256, 0, stream>>>(x, sbbase, ssrc, xjp, N);
        mlp_kernel<false><<<mgrid, 256, 0, stream>>>(x, (const unsigned*)xjp, W, b, out, N);
    } else {
        // Tier C: atomic fallback
        size_t need2 = (size_t)N * 64 * 4;
        unsigned int* scratch = (ws_size >= need2) ? (unsigned int*)d_ws : (unsigned int*)d_out;
        init_kernel<<<2048, 256, 0, stream>>>((uint4*)scratch, N * 16);
        long long sthreads = (long long)E * 64;
        int sblocks = (int)((sthreads + 255) / 256);
        scatter_kernel<<<sblocks, 256, 0, stream>>>(x, ei, scratch, E);
        mlp_kernel<true><<<mgrid, 256, 0, stream>>>(x, scratch, W, b, out, N);
    }
}